// Round 1
// baseline (1743.035 us; speedup 1.0000x reference)
//
#include <hip/hip_runtime.h>
#include <math.h>

typedef _Float16 f16;
typedef _Float16 f16x8 __attribute__((ext_vector_type(8)));
typedef float f32x4 __attribute__((ext_vector_type(4)));

#define NSTEP 128
#define FEAT  127
#define BLK_B 16
#define NBLOCK 256
#define NTHREADS 512

__device__ __forceinline__ float sigf(float x) { return 1.0f / (1.0f + __expf(-x)); }
// tanh(x) = 1 - 2/(1+e^{2x}) ; saturates correctly at +-inf
__device__ __forceinline__ float tanh_(float x) { return 1.0f - 2.0f / (1.0f + __expf(2.0f * x)); }

// Convert fp32 weights into f16 MFMA B-fragments in d_ws.
// Fragment layout (16x16x32 f16): lane holds B[k=quad*8+j][n=lane&15],
// i.e. W[n_global][k_global] with n_global = gate*128 + wave*16 + (lane&15),
// k_global = ks*32 + (lane>>4)*8 + j ;  k<128 -> w_ih, k>=128 -> w_hh.
// ws index: ((((layer*8+wave)*4+gate)*8+ks)*64+lane)*8+j  -> lane reads 16B coalesced.
__global__ void prep_weights(const float* __restrict__ w_ih0,
                             const float* __restrict__ w_hh0,
                             const float* __restrict__ w_ih1,
                             const float* __restrict__ w_hh1,
                             f16* __restrict__ ws16)
{
    int idx = blockIdx.x * blockDim.x + threadIdx.x;  // 0 .. 262143
    int j     = idx & 7;
    int lane  = (idx >> 3) & 63;
    int ks    = (idx >> 9) & 7;
    int gate  = (idx >> 12) & 3;
    int wave  = (idx >> 14) & 7;
    int layer = (idx >> 17) & 1;
    int n = gate * 128 + wave * 16 + (lane & 15);
    int k = ks * 32 + (lane >> 4) * 8 + j;
    float v;
    if (layer == 0) v = (k < 128) ? w_ih0[n * 128 + k] : w_hh0[n * 128 + (k - 128)];
    else            v = (k < 128) ? w_ih1[n * 128 + k] : w_hh1[n * 128 + (k - 128)];
    ws16[idx] = (f16)v;
}

// One block = 16 batch rows, full time loop. 8 waves; wave w owns gates
// u in [16w, 16w+16) for BOTH layers (i/f/g/o aligned -> LSTM cell in regs).
__global__ __launch_bounds__(NTHREADS, 2) void lstm_main(
    const float* __restrict__ nf,   const float* __restrict__ tgt,
    const float* __restrict__ b_ih0, const float* __restrict__ b_hh0,
    const float* __restrict__ b_ih1, const float* __restrict__ b_hh1,
    const float* __restrict__ w_out, const float* __restrict__ b_out,
    const f16* __restrict__ wfrag,  float* __restrict__ out)
{
    // stride 152 halfs = 304B: 16B-aligned rows, bank advance 12 dwords/row -> <=2-way conflicts
    __shared__ f16 xs[16][152];
    __shared__ f16 h0s[2][16][152];
    __shared__ f16 h1s[2][16][152];
    __shared__ float outp[8][16];

    const int tid  = threadIdx.x;
    const int wave = tid >> 6;
    const int lane = tid & 63;
    const int col  = lane & 15;     // MFMA n / gate-within-group ; also A-frag m
    const int quad = lane >> 4;     // MFMA k-quad ; C/D row group
    const int b0   = blockIdx.x * BLK_B;
    const int u    = wave * 16 + col;   // hidden unit owned by this lane

    // zero initial h state (both parity buffers)
    for (int i = tid; i < 2 * 16 * 152; i += NTHREADS) {
        (&h0s[0][0][0])[i] = (f16)0.0f;
        (&h1s[0][0][0])[i] = (f16)0.0f;
    }

    float bias0[4], bias1[4];
#pragma unroll
    for (int g = 0; g < 4; ++g) {
        bias0[g] = b_ih0[g * 128 + u] + b_hh0[g * 128 + u];
        bias1[g] = b_ih1[g * 128 + u] + b_hh1[g * 128 + u];
    }
    const float wo_u = w_out[u];
    const float bout = b_out[0];

    f32x4 c0 = {0.f, 0.f, 0.f, 0.f};
    f32x4 c1 = {0.f, 0.f, 0.f, 0.f};

    const f16x8* wf = (const f16x8*)wfrag;   // 16B fragments

    __syncthreads();

    for (int t = 0; t < NSTEP; ++t) {
        const int pa = t & 1;        // read-parity for h
        const int wb = pa ^ 1;       // write-parity

        // ---- stage x_t into LDS (f16). wave w loads rows 2w, 2w+1.
#pragma unroll
        for (int rr = 0; rr < 2; ++rr) {
            const int row = wave * 2 + rr;
            const long gbt = (long)(b0 + row) * NSTEP + t;
#pragma unroll
            for (int h = 0; h < 2; ++h) {
                const int k = lane + 64 * h;
                float v;
                if (k < FEAT) v = nf[gbt * FEAT + k];
                else          v = (t > 0) ? tgt[(long)(b0 + row) * NSTEP + (t - 1)] : 0.0f;
                xs[row][k] = (f16)v;
            }
        }
        __syncthreads();  // A: xs ready; prev step's h1 writes visible

        // ---- layer 0: gates0 = [x | h0_prev] @ W0^T + biases
        f32x4 acc[4];
#pragma unroll
        for (int g = 0; g < 4; ++g)
            acc[g] = (f32x4){bias0[g], bias0[g], bias0[g], bias0[g]};
#pragma unroll
        for (int ks = 0; ks < 8; ++ks) {
            const f16* ap = (ks < 4) ? &xs[col][ks * 32 + quad * 8]
                                     : &h0s[pa][col][(ks - 4) * 32 + quad * 8];
            f16x8 a = *(const f16x8*)ap;
#pragma unroll
            for (int g = 0; g < 4; ++g) {
                f16x8 b = wf[(((0 * 8 + wave) * 4 + g) * 8 + ks) * 64 + lane];
                acc[g] = __builtin_amdgcn_mfma_f32_16x16x32_f16(a, b, acc[g], 0, 0, 0);
            }
        }
        // LSTM cell 0 (in registers; lane owns (batch=quad*4+r, unit=u))
        float h0n[4];
#pragma unroll
        for (int r = 0; r < 4; ++r) {
            const float ig = sigf(acc[0][r]);
            const float fg = sigf(acc[1][r]);
            const float gg = tanh_(acc[2][r]);
            const float og = sigf(acc[3][r]);
            const float cn = fg * c0[r] + ig * gg;
            c0[r] = cn;
            h0n[r] = og * tanh_(cn);
        }
#pragma unroll
        for (int r = 0; r < 4; ++r)
            h0s[wb][quad * 4 + r][u] = (f16)h0n[r];

        __syncthreads();  // M: h0_new complete

        // ---- layer 1: gates1 = [h0_new | h1_prev] @ W1^T + biases
#pragma unroll
        for (int g = 0; g < 4; ++g)
            acc[g] = (f32x4){bias1[g], bias1[g], bias1[g], bias1[g]};
#pragma unroll
        for (int ks = 0; ks < 8; ++ks) {
            const f16* ap = (ks < 4) ? &h0s[wb][col][ks * 32 + quad * 8]
                                     : &h1s[pa][col][(ks - 4) * 32 + quad * 8];
            f16x8 a = *(const f16x8*)ap;
#pragma unroll
            for (int g = 0; g < 4; ++g) {
                f16x8 b = wf[(((1 * 8 + wave) * 4 + g) * 8 + ks) * 64 + lane];
                acc[g] = __builtin_amdgcn_mfma_f32_16x16x32_f16(a, b, acc[g], 0, 0, 0);
            }
        }
        float h1n[4];
#pragma unroll
        for (int r = 0; r < 4; ++r) {
            const float ig = sigf(acc[0][r]);
            const float fg = sigf(acc[1][r]);
            const float gg = tanh_(acc[2][r]);
            const float og = sigf(acc[3][r]);
            const float cn = fg * c1[r] + ig * gg;
            c1[r] = cn;
            h1n[r] = og * tanh_(cn);
        }
#pragma unroll
        for (int r = 0; r < 4; ++r)
            h1s[wb][quad * 4 + r][u] = (f16)h1n[r];

        // partial output dot: sum over this wave's 16 units
        float ps[4];
#pragma unroll
        for (int r = 0; r < 4; ++r) ps[r] = h1n[r] * wo_u;
#pragma unroll
        for (int m = 1; m < 16; m <<= 1) {
#pragma unroll
            for (int r = 0; r < 4; ++r) ps[r] += __shfl_xor(ps[r], m, 64);
        }
        if (col == 0) {
#pragma unroll
            for (int r = 0; r < 4; ++r) outp[wave][quad * 4 + r] = ps[r];
        }

        __syncthreads();  // B: h1_new + partials complete

        if (tid < 16) {
            float s = bout;
#pragma unroll
            for (int w = 0; w < 8; ++w) s += outp[w][tid];
            out[(long)(b0 + tid) * NSTEP + t] = sigf(s);
        }
    }
}

extern "C" void kernel_launch(void* const* d_in, const int* in_sizes, int n_in,
                              void* d_out, int out_size, void* d_ws, size_t ws_size,
                              hipStream_t stream)
{
    const float* nf    = (const float*)d_in[0];
    const float* tgt   = (const float*)d_in[1];
    const float* w_ih0 = (const float*)d_in[2];
    const float* w_hh0 = (const float*)d_in[3];
    const float* b_ih0 = (const float*)d_in[4];
    const float* b_hh0 = (const float*)d_in[5];
    const float* w_ih1 = (const float*)d_in[6];
    const float* w_hh1 = (const float*)d_in[7];
    const float* b_ih1 = (const float*)d_in[8];
    const float* b_hh1 = (const float*)d_in[9];
    const float* w_out = (const float*)d_in[10];
    const float* b_out = (const float*)d_in[11];

    f16*   ws16 = (f16*)d_ws;       // 512 KB of f16 weight fragments
    float* out  = (float*)d_out;

    prep_weights<<<1024, 256, 0, stream>>>(w_ih0, w_hh0, w_ih1, w_hh1, ws16);
    lstm_main<<<NBLOCK, NTHREADS, 0, stream>>>(nf, tgt, b_ih0, b_hh0, b_ih1, b_hh1,
                                               w_out, b_out, ws16, out);
}